// Round 11
// baseline (183.033 us; speedup 1.0000x reference)
//
#include <hip/hip_runtime.h>

#define NN 50000
#define EE 800000
#define D 128
#define NCLS 3
#define MIDX 10000
#define NB 196           // coarse buckets = ceil(NN/256)
#define CHUNK 4096       // edges per WG in fill_coarse
#define HIST_WGS 98      // 98 * 8192 >= EE
#define WCONV_WGS 64     // D*D/256
#define LIN1_WGS 782     // ceil(NN/64)

typedef unsigned int uint32;
typedef unsigned short ushort16;
typedef __attribute__((ext_vector_type(8))) short short8;
typedef __attribute__((ext_vector_type(4))) float f32x4;

__device__ __forceinline__ ushort16 f2bf(float f) {
    uint32 u = __float_as_uint(f);
    u = (u + 0x7fffu + ((u >> 16) & 1u)) >> 16;  // round-to-nearest-even
    return (ushort16)u;
}
__device__ __forceinline__ float bflo(uint32 packed) {
    return __uint_as_float(packed << 16);
}
__device__ __forceinline__ float bfhi(uint32 packed) {
    return __uint_as_float(packed & 0xFFFF0000u);
}

// full-wave gather, 16 row loads in flight
__device__ __forceinline__ void gather_rows(const uint32* __restrict__ h,
                                            const int* __restrict__ esrc,
                                            int beg, int end, int lane,
                                            float& a0, float& a1) {
    int i = beg;
    for (; i + 16 <= end; i += 16) {
        int s[16];
        uint32 q[16];
#pragma unroll
        for (int k = 0; k < 16; ++k) s[k] = esrc[i + k];
#pragma unroll
        for (int k = 0; k < 16; ++k) q[k] = h[(long long)s[k] * (D / 2) + lane];
        float t0a = 0.f, t0b = 0.f, t1a = 0.f, t1b = 0.f;
#pragma unroll
        for (int k = 0; k < 16; k += 2) {
            t0a += bflo(q[k]);     t1a += bfhi(q[k]);
            t0b += bflo(q[k + 1]); t1b += bfhi(q[k + 1]);
        }
        a0 += t0a + t0b;
        a1 += t1a + t1b;
    }
    for (; i + 4 <= end; i += 4) {
        int s[4];
        uint32 q[4];
#pragma unroll
        for (int k = 0; k < 4; ++k) s[k] = esrc[i + k];
#pragma unroll
        for (int k = 0; k < 4; ++k) q[k] = h[(long long)s[k] * (D / 2) + lane];
        a0 += (bflo(q[0]) + bflo(q[1])) + (bflo(q[2]) + bflo(q[3]));
        a1 += (bfhi(q[0]) + bfhi(q[1])) + (bfhi(q[2]) + bfhi(q[3]));
    }
    for (; i < end; ++i) {
        const uint32 q = h[(long long)esrc[i] * (D / 2) + lane];
        a0 += bflo(q);
        a1 += bfhi(q);
    }
}

// ---- K1: prep (W -> bf16) + coarse hist ---------------------------------

__global__ __launch_bounds__(256) void prep_hist(const float* __restrict__ W1,
                                                 const float* __restrict__ W2,
                                                 const float* __restrict__ W3,
                                                 const int* __restrict__ dst,
                                                 ushort16* __restrict__ Wbf,
                                                 int* __restrict__ hpart) {
    const int t = threadIdx.x;
    if (blockIdx.x < WCONV_WGS) {
        const int i = blockIdx.x * 256 + t;
        Wbf[i] = f2bf(W1[i]);
        Wbf[i + D * D] = f2bf(W2[i]);
        Wbf[i + 2 * D * D] = f2bf(W3[i]);
    } else {
        __shared__ int hcnt[256];
        const int b = blockIdx.x - WCONV_WGS;
        hcnt[t] = 0;
        __syncthreads();
        const int e0 = b * 8192;
        const int e1 = (e0 + 8192 < EE) ? e0 + 8192 : EE;
        for (int s = e0 + t; s < e1; s += 256) atomicAdd(&hcnt[dst[s] >> 8], 1);
        __syncthreads();
        hpart[b * 256 + t] = hcnt[t];
    }
}

// ---- K2: block 0 = coarse scan; blocks 1.. = layer-1 MFMA linear --------

__global__ __launch_bounds__(256) void scan_linear1(const int* __restrict__ hpart,
                                                    int* __restrict__ bstart,
                                                    int* __restrict__ bcursor,
                                                    int* __restrict__ rowptr,
                                                    const float* __restrict__ x,
                                                    const ushort16* __restrict__ Wbf,
                                                    const float* __restrict__ bias,
                                                    ushort16* __restrict__ h) {
    if (blockIdx.x == 0) {
        __shared__ int s[256];
        const int t = threadIdx.x;
        int v = 0;
        if (t < NB)
            for (int w = 0; w < HIST_WGS; ++w) v += hpart[w * 256 + t];
        s[t] = v;
        __syncthreads();
        for (int off = 1; off < 256; off <<= 1) {
            const int add = (t >= off) ? s[t - off] : 0;
            __syncthreads();
            s[t] += add;
            __syncthreads();
        }
        const int excl = s[t] - v;
        if (t < NB) {
            bstart[t] = excl;
            bcursor[t * 16] = excl;
        }
        if (t == NB - 1) bstart[NB] = excl + v;  // == EE
        if (t == 0) rowptr[NN] = EE;
        return;
    }
    // ---- linear1: h1 = bf16(x0 @ W1^T + b1), fp32 input ----
    const int wave = threadIdx.x >> 6;
    const int lane = threadIdx.x & 63;
    const int m0 = (blockIdx.x - 1) * 64 + wave * 16;
    if (m0 >= NN) return;
    const int lr = lane & 15;
    const int lk = (lane >> 4) * 8;

    f32x4 acc[8] = {};
#pragma unroll
    for (int k4 = 0; k4 < 4; ++k4) {
        const int kb = k4 * 32 + lk;
        const float4* xp = (const float4*)(x + (long long)(m0 + lr) * D + kb);
        const float4 a0 = xp[0];
        const float4 a1 = xp[1];
        short8 af;
        af[0] = (short)f2bf(a0.x); af[1] = (short)f2bf(a0.y);
        af[2] = (short)f2bf(a0.z); af[3] = (short)f2bf(a0.w);
        af[4] = (short)f2bf(a1.x); af[5] = (short)f2bf(a1.y);
        af[6] = (short)f2bf(a1.z); af[7] = (short)f2bf(a1.w);
#pragma unroll
        for (int nt = 0; nt < 8; ++nt) {
            const short8 bfrag = *(const short8*)(Wbf + (nt * 16 + lr) * D + kb);
            acc[nt] = __builtin_amdgcn_mfma_f32_16x16x32_bf16(af, bfrag, acc[nt], 0, 0, 0);
        }
    }
    const int rbase = m0 + (lane >> 4) * 4;
#pragma unroll
    for (int nt = 0; nt < 8; ++nt) {
        const int f = nt * 16 + lr;
        const float bb = bias[f];
#pragma unroll
        for (int r = 0; r < 4; ++r)
            h[(long long)(rbase + r) * D + f] = f2bf(acc[nt][r] + bb);
    }
}

// ---- K3: per-WG LDS hist, reserve slabs, write packed -------------------

__global__ __launch_bounds__(256) void fill_coarse(const int* __restrict__ src,
                                                   const int* __restrict__ dst,
                                                   int* __restrict__ bcursor,
                                                   int* __restrict__ espacked) {
    __shared__ int hcnt[256];
    __shared__ int hbase[256];
    const int t = threadIdx.x;
    const int e0 = blockIdx.x * CHUNK;
    const int e1 = (e0 + CHUNK < EE) ? e0 + CHUNK : EE;
    hcnt[t] = 0;
    __syncthreads();
    for (int s = e0 + t; s < e1; s += 256) atomicAdd(&hcnt[dst[s] >> 8], 1);
    __syncthreads();
    if (t < NB) {
        const int c = hcnt[t];
        hbase[t] = c ? atomicAdd(&bcursor[t * 16], c) : 0;
    }
    hcnt[t] = 0;
    __syncthreads();
    for (int s = e0 + t; s < e1; s += 256) {
        const int d = dst[s];
        const int b = d >> 8;
        const int r = atomicAdd(&hcnt[b], 1);
        espacked[hbase[b] + r] = (src[s] << 8) | (d & 255);
    }
}

// ---- K4: per bucket: LDS count -> scan -> rowptr -> scatter -------------

__global__ __launch_bounds__(256) void bucket_scatter(const int* __restrict__ espacked,
                                                      const int* __restrict__ bstart,
                                                      int* __restrict__ rowptr,
                                                      int* __restrict__ esrc) {
    __shared__ int cnt[256];
    __shared__ int sc[256];
    __shared__ int cur[256];
    const int b = blockIdx.x;
    const int t = threadIdx.x;
    const int n0 = b * 256;
    const int seg0 = bstart[b];
    const int seg1 = bstart[b + 1];
    cnt[t] = 0;
    __syncthreads();
    for (int s = seg0 + t; s < seg1; s += 256) atomicAdd(&cnt[espacked[s] & 255], 1);
    __syncthreads();
    const int v = cnt[t];
    sc[t] = v;
    __syncthreads();
    for (int off = 1; off < 256; off <<= 1) {
        const int add = (t >= off) ? sc[t - off] : 0;
        __syncthreads();
        sc[t] += add;
        __syncthreads();
    }
    const int excl = seg0 + sc[t] - v;
    if (n0 + t < NN) rowptr[n0 + t] = excl;
    cur[t] = excl;
    __syncthreads();
    for (int s = seg0 + t; s < seg1; s += 256) {
        const int p = espacked[s];
        const int pos = atomicAdd(&cur[p & 255], 1);
        esrc[pos] = p >> 8;
    }
}

// ---- K5/K6: FUSED aggregate -> relu -> LDS tile -> MFMA next linear -----
// 512 threads / 8 waves per block; 16 nodes; 2 nodes per wave (less serial
// latency exposure per wave than the old 4); MFMA: 1 f-tile per wave.

__global__ __launch_bounds__(512) void agg_linear(const uint32* __restrict__ h,
                                                  const int* __restrict__ rowptr,
                                                  const int* __restrict__ esrc,
                                                  const ushort16* __restrict__ Wbf,
                                                  const float* __restrict__ bias,
                                                  ushort16* __restrict__ hnext) {
    __shared__ uint32 xs[16][68];
    const int wave = threadIdx.x >> 6;   // 0..7
    const int lane = threadIdx.x & 63;
    const int m0 = blockIdx.x * 16;

#pragma unroll
    for (int j = 0; j < 2; ++j) {
        const int row = wave * 2 + j;
        const int node = __builtin_amdgcn_readfirstlane(m0 + row);
        const int beg = rowptr[node];
        const int end = rowptr[node + 1];
        const uint32 p = h[(long long)node * (D / 2) + lane];
        float acc0 = bflo(p), acc1 = bfhi(p);
        gather_rows(h, esrc, beg, end, lane, acc0, acc1);
        xs[row][lane] = ((uint32)f2bf(fmaxf(acc1, 0.f)) << 16) |
                        (uint32)f2bf(fmaxf(acc0, 0.f));
    }
    __syncthreads();

    const int lr = lane & 15;
    const int lk = (lane >> 4) * 8;
    f32x4 acc = {};
#pragma unroll
    for (int k4 = 0; k4 < 4; ++k4) {
        const int kb = k4 * 32 + lk;
        const short8 af = *(const short8*)&xs[lr][kb >> 1];
        const short8 bfrag = *(const short8*)(Wbf + (wave * 16 + lr) * D + kb);
        acc = __builtin_amdgcn_mfma_f32_16x16x32_bf16(af, bfrag, acc, 0, 0, 0);
    }
    const int rbase = m0 + (lane >> 4) * 4;
    const int col = wave * 16 + lr;
    const float bb = bias[col];
#pragma unroll
    for (int r = 0; r < 4; ++r)
        hnext[(long long)(rbase + r) * D + col] = f2bf(acc[r] + bb);
}

// ---- K7: last aggregate -> fp32 xe + fused head -------------------------

__global__ __launch_bounds__(256) void agg_head(const uint32* __restrict__ h,
                                                const int* __restrict__ rowptr,
                                                const int* __restrict__ esrc,
                                                float* __restrict__ xe,
                                                const float* __restrict__ Wout,
                                                const float* __restrict__ bout,
                                                float* __restrict__ logits,
                                                float* __restrict__ ypred) {
    const int wave = threadIdx.x >> 6;
    const int lane = threadIdx.x & 63;
    const int node = __builtin_amdgcn_readfirstlane(blockIdx.x * 4 + wave);
    if (node >= NN) return;
    const int beg = rowptr[node];
    const int end = rowptr[node + 1];
    const uint32 p = h[(long long)node * (D / 2) + lane];
    float acc0 = bflo(p), acc1 = bfhi(p);
    gather_rows(h, esrc, beg, end, lane, acc0, acc1);
    const float r0 = fmaxf(acc0, 0.f);
    const float r1 = fmaxf(acc1, 0.f);
    float2 r;
    r.x = r0;
    r.y = r1;
    ((float2*)(xe + (long long)node * D))[lane] = r;

    const float2 w0 = ((const float2*)(Wout + 0 * D))[lane];
    const float2 w1 = ((const float2*)(Wout + 1 * D))[lane];
    const float2 w2 = ((const float2*)(Wout + 2 * D))[lane];
    float l0 = r0 * w0.x + r1 * w0.y;
    float l1 = r0 * w1.x + r1 * w1.y;
    float l2 = r0 * w2.x + r1 * w2.y;
#pragma unroll
    for (int off = 32; off > 0; off >>= 1) {
        l0 += __shfl_xor(l0, off, 64);
        l1 += __shfl_xor(l1, off, 64);
        l2 += __shfl_xor(l2, off, 64);
    }
    if (lane == 0) {
        l0 += bout[0]; l1 += bout[1]; l2 += bout[2];
        logits[node * 3 + 0] = l0;
        logits[node * 3 + 1] = l1;
        logits[node * 3 + 2] = l2;
        int best = 0;
        float bv = l0;
        if (l1 > bv) { bv = l1; best = 1; }
        if (l2 > bv) { bv = l2; best = 2; }
        ypred[node] = (float)best;
    }
}

// ---- K8: epilogue gather ------------------------------------------------

__global__ void gather_out(const float* __restrict__ logits, const float* __restrict__ ypred,
                           const int* __restrict__ nidx, float* __restrict__ node_out,
                           float* __restrict__ y_nodepred) {
    const int m = blockIdx.x * blockDim.x + threadIdx.x;
    if (m >= MIDX) return;
    const int n = nidx[m];
    node_out[m * 3 + 0] = logits[n * 3 + 0];
    node_out[m * 3 + 1] = logits[n * 3 + 1];
    node_out[m * 3 + 2] = logits[n * 3 + 2];
    y_nodepred[m] = ypred[n];
}

extern "C" void kernel_launch(void* const* d_in, const int* in_sizes, int n_in,
                              void* d_out, int out_size, void* d_ws, size_t ws_size,
                              hipStream_t stream) {
    const float* x0 = (const float*)d_in[0];
    const int* ei = (const int*)d_in[1];
    const int* src = ei;        // edge_index[0]
    const int* dst = ei + EE;   // edge_index[1]
    const int* nidx = (const int*)d_in[3];
    const float* W1 = (const float*)d_in[4];
    const float* b1 = (const float*)d_in[5];
    const float* W2 = (const float*)d_in[6];
    const float* b2 = (const float*)d_in[7];
    const float* W3 = (const float*)d_in[8];
    const float* b3 = (const float*)d_in[9];
    const float* Wout = (const float*)d_in[10];
    const float* bout = (const float*)d_in[11];

    char* ws = (char*)d_ws;
    ushort16* hbuf = (ushort16*)ws;                                // N*D bf16  (buffer A)
    ushort16* xbuf = hbuf + (long long)NN * D;                     // N*D bf16  (buffer B)
    ushort16* Wbf  = xbuf + (long long)NN * D;                     // 3*D*D bf16
    float* logits  = (float*)(Wbf + 3 * D * D);                    // N*3
    int* rowptr    = (int*)(logits + (long long)NN * NCLS);        // NN+1 (+pad)
    int* hpart     = rowptr + NN + 4;                              // HIST_WGS*256
    int* bstart    = hpart + HIST_WGS * 256;                       // NB+1 (pad 256)
    int* bcursor   = bstart + 256;                                 // NB*16
    int* espacked  = bcursor + NB * 16 + 12;                       // EE
    int* esrc      = espacked + EE;                                // EE

    float* out = (float*)d_out;
    float* xe       = out;                       // N*D
    float* node_out = out + (long long)NN * D;   // M*3
    float* yp       = node_out + MIDX * NCLS;    // N
    float* ynp      = yp + NN;                   // M

    // ---- K1..K4: prep + CSR build (linear1 overlapped in K2) ----
    prep_hist<<<WCONV_WGS + HIST_WGS, 256, 0, stream>>>(W1, W2, W3, dst, Wbf, hpart);
    scan_linear1<<<1 + LIN1_WGS, 256, 0, stream>>>(hpart, bstart, bcursor, rowptr,
                                                   x0, Wbf, b1, hbuf);
    fill_coarse<<<(EE + CHUNK - 1) / CHUNK, 256, 0, stream>>>(src, dst, bcursor, espacked);
    bucket_scatter<<<NB, 256, 0, stream>>>(espacked, bstart, rowptr, esrc);

    // ---- K5..K8: layers + head ----
    agg_linear<<<NN / 16, 512, 0, stream>>>((const uint32*)hbuf, rowptr, esrc,
                                            Wbf + (long long)D * D, b2, xbuf);           // A -> B (h2)
    agg_linear<<<NN / 16, 512, 0, stream>>>((const uint32*)xbuf, rowptr, esrc,
                                            Wbf + 2LL * D * D, b3, hbuf);                // B -> A (h3)
    agg_head<<<(NN + 3) / 4, 256, 0, stream>>>((const uint32*)hbuf, rowptr, esrc,
                                               xe, Wout, bout, logits, yp);
    gather_out<<<(MIDX + 255) / 256, 256, 0, stream>>>(logits, yp, nidx, node_out, ynp);
}

// Round 12
// 174.793 us; speedup vs baseline: 1.0471x; 1.0471x over previous
//
#include <hip/hip_runtime.h>

#define NN 50000
#define EE 800000
#define D 128
#define NCLS 3
#define MIDX 10000
#define NB 196           // coarse buckets = ceil(NN/256)
#define CHUNK 4096       // edges per WG in fill_coarse
#define HIST_WGS 98      // 98 * 8192 >= EE
#define WCONV_WGS 64     // D*D/256
#define SCAT_WGS NB      // scatter blocks in merged kernel
#define LIN1_WGS 782     // ceil(NN/64)

typedef unsigned int uint32;
typedef unsigned short ushort16;
typedef __attribute__((ext_vector_type(8))) short short8;
typedef __attribute__((ext_vector_type(4))) float f32x4;

__device__ __forceinline__ ushort16 f2bf(float f) {
    uint32 u = __float_as_uint(f);
    u = (u + 0x7fffu + ((u >> 16) & 1u)) >> 16;  // round-to-nearest-even
    return (ushort16)u;
}
__device__ __forceinline__ float bflo(uint32 packed) {
    return __uint_as_float(packed << 16);
}
__device__ __forceinline__ float bfhi(uint32 packed) {
    return __uint_as_float(packed & 0xFFFF0000u);
}

// full-wave gather, 16 row loads in flight (round-8/10 best variant)
__device__ __forceinline__ void gather_rows(const uint32* __restrict__ h,
                                            const int* __restrict__ esrc,
                                            int beg, int end, int lane,
                                            float& a0, float& a1) {
    int i = beg;
    for (; i + 16 <= end; i += 16) {
        int s[16];
        uint32 q[16];
#pragma unroll
        for (int k = 0; k < 16; ++k) s[k] = esrc[i + k];
#pragma unroll
        for (int k = 0; k < 16; ++k) q[k] = h[(long long)s[k] * (D / 2) + lane];
        float t0a = 0.f, t0b = 0.f, t1a = 0.f, t1b = 0.f;
#pragma unroll
        for (int k = 0; k < 16; k += 2) {
            t0a += bflo(q[k]);     t1a += bfhi(q[k]);
            t0b += bflo(q[k + 1]); t1b += bfhi(q[k + 1]);
        }
        a0 += t0a + t0b;
        a1 += t1a + t1b;
    }
    for (; i + 4 <= end; i += 4) {
        int s[4];
        uint32 q[4];
#pragma unroll
        for (int k = 0; k < 4; ++k) s[k] = esrc[i + k];
#pragma unroll
        for (int k = 0; k < 4; ++k) q[k] = h[(long long)s[k] * (D / 2) + lane];
        a0 += (bflo(q[0]) + bflo(q[1])) + (bflo(q[2]) + bflo(q[3]));
        a1 += (bfhi(q[0]) + bfhi(q[1])) + (bfhi(q[2]) + bfhi(q[3]));
    }
    for (; i < end; ++i) {
        const uint32 q = h[(long long)esrc[i] * (D / 2) + lane];
        a0 += bflo(q);
        a1 += bfhi(q);
    }
}

// 196-wide exclusive scan of gbucket in LDS; returns exclusive prefix in sc[t]
// (sc has 256 entries; t >= NB lanes contribute 0)
__device__ __forceinline__ void bucket_scan(const int* __restrict__ gbucket,
                                            int* sc, int t, int& v) {
    v = (t < NB) ? gbucket[t] : 0;
    sc[t] = v;
    __syncthreads();
    for (int off = 1; off < 256; off <<= 1) {
        const int add = (t >= off) ? sc[t - off] : 0;
        __syncthreads();
        sc[t] += add;
        __syncthreads();
    }
    // sc[t] is inclusive; caller uses sc[t]-v as exclusive
}

// ---- K1: prep (W -> bf16) + coarse hist (atomic into zeroed gbucket) ----

__global__ __launch_bounds__(256) void prep_hist(const float* __restrict__ W1,
                                                 const float* __restrict__ W2,
                                                 const float* __restrict__ W3,
                                                 const int* __restrict__ dst,
                                                 ushort16* __restrict__ Wbf,
                                                 int* __restrict__ gbucket) {
    const int t = threadIdx.x;
    if (blockIdx.x < WCONV_WGS) {
        const int i = blockIdx.x * 256 + t;
        Wbf[i] = f2bf(W1[i]);
        Wbf[i + D * D] = f2bf(W2[i]);
        Wbf[i + 2 * D * D] = f2bf(W3[i]);
    } else {
        __shared__ int hcnt[256];
        const int b = blockIdx.x - WCONV_WGS;
        hcnt[t] = 0;
        __syncthreads();
        const int e0 = b * 8192;
        const int e1 = (e0 + 8192 < EE) ? e0 + 8192 : EE;
        for (int s = e0 + t; s < e1; s += 256) atomicAdd(&hcnt[dst[s] >> 8], 1);
        __syncthreads();
        if (t < NB && hcnt[t]) atomicAdd(&gbucket[t], hcnt[t]);
    }
}

// ---- K2: per-WG LDS hist, per-block bucket scan, reserve slabs, write packed

__global__ __launch_bounds__(256) void fill_coarse(const int* __restrict__ src,
                                                   const int* __restrict__ dst,
                                                   const int* __restrict__ gbucket,
                                                   int* __restrict__ bcursor,
                                                   int* __restrict__ espacked) {
    __shared__ int sc[256];
    __shared__ int hcnt[256];
    __shared__ int hbase[256];
    const int t = threadIdx.x;
    int v;
    bucket_scan(gbucket, sc, t, v);
    const int bstart_t = sc[t] - v;  // exclusive prefix = bucket start
    const int e0 = blockIdx.x * CHUNK;
    const int e1 = (e0 + CHUNK < EE) ? e0 + CHUNK : EE;
    hcnt[t] = 0;
    __syncthreads();
    for (int s = e0 + t; s < e1; s += 256) atomicAdd(&hcnt[dst[s] >> 8], 1);
    __syncthreads();
    if (t < NB) {
        const int c = hcnt[t];
        hbase[t] = c ? (bstart_t + atomicAdd(&bcursor[t * 16], c)) : 0;
    }
    hcnt[t] = 0;
    __syncthreads();
    for (int s = e0 + t; s < e1; s += 256) {
        const int d = dst[s];
        const int b = d >> 8;
        const int r = atomicAdd(&hcnt[b], 1);
        espacked[hbase[b] + r] = (src[s] << 8) | (d & 255);
    }
}

// ---- K3: blocks 0..NB-1 = bucket scatter; blocks NB.. = layer-1 linear --

__global__ __launch_bounds__(256) void scatter_linear1(const int* __restrict__ espacked,
                                                       const int* __restrict__ gbucket,
                                                       int* __restrict__ rowptr,
                                                       int* __restrict__ esrc,
                                                       const float* __restrict__ x,
                                                       const ushort16* __restrict__ Wbf,
                                                       const float* __restrict__ bias,
                                                       ushort16* __restrict__ h) {
    const int t = threadIdx.x;
    if (blockIdx.x < SCAT_WGS) {
        __shared__ int sc[256];
        __shared__ int cnt[256];
        __shared__ int cur[256];
        __shared__ int segs[2];
        const int b = blockIdx.x;
        int v;
        bucket_scan(gbucket, sc, t, v);
        if (t == b) {
            segs[0] = sc[t] - v;      // seg0 = bucket start
            segs[1] = sc[t];          // seg1 = bucket end
        }
        __syncthreads();
        const int seg0 = segs[0];
        const int seg1 = segs[1];
        const int n0 = b * 256;
        cnt[t] = 0;
        __syncthreads();
        for (int s = seg0 + t; s < seg1; s += 256) atomicAdd(&cnt[espacked[s] & 255], 1);
        __syncthreads();
        const int c = cnt[t];
        sc[t] = c;
        __syncthreads();
        for (int off = 1; off < 256; off <<= 1) {
            const int add = (t >= off) ? sc[t - off] : 0;
            __syncthreads();
            sc[t] += add;
            __syncthreads();
        }
        const int excl = seg0 + sc[t] - c;
        if (n0 + t < NN) rowptr[n0 + t] = excl;
        if (b == 0 && t == 0) rowptr[NN] = EE;
        cur[t] = excl;
        __syncthreads();
        for (int s = seg0 + t; s < seg1; s += 256) {
            const int p = espacked[s];
            const int pos = atomicAdd(&cur[p & 255], 1);
            esrc[pos] = p >> 8;
        }
        return;
    }
    // ---- linear1: h1 = bf16(x0 @ W1^T + b1), fp32 input ----
    const int wave = t >> 6;
    const int lane = t & 63;
    const int m0 = (blockIdx.x - SCAT_WGS) * 64 + wave * 16;
    if (m0 >= NN) return;
    const int lr = lane & 15;
    const int lk = (lane >> 4) * 8;

    f32x4 acc[8] = {};
#pragma unroll
    for (int k4 = 0; k4 < 4; ++k4) {
        const int kb = k4 * 32 + lk;
        const float4* xp = (const float4*)(x + (long long)(m0 + lr) * D + kb);
        const float4 a0 = xp[0];
        const float4 a1 = xp[1];
        short8 af;
        af[0] = (short)f2bf(a0.x); af[1] = (short)f2bf(a0.y);
        af[2] = (short)f2bf(a0.z); af[3] = (short)f2bf(a0.w);
        af[4] = (short)f2bf(a1.x); af[5] = (short)f2bf(a1.y);
        af[6] = (short)f2bf(a1.z); af[7] = (short)f2bf(a1.w);
#pragma unroll
        for (int nt = 0; nt < 8; ++nt) {
            const short8 bfrag = *(const short8*)(Wbf + (nt * 16 + lr) * D + kb);
            acc[nt] = __builtin_amdgcn_mfma_f32_16x16x32_bf16(af, bfrag, acc[nt], 0, 0, 0);
        }
    }
    const int rbase = m0 + (lane >> 4) * 4;
#pragma unroll
    for (int nt = 0; nt < 8; ++nt) {
        const int f = nt * 16 + lr;
        const float bb = bias[f];
#pragma unroll
        for (int r = 0; r < 4; ++r)
            h[(long long)(rbase + r) * D + f] = f2bf(acc[nt][r] + bb);
    }
}

// ---- K4/K5: FUSED aggregate -> relu -> LDS tile -> MFMA next linear -----
// (round-10 best config: 256 threads, 4 waves, 4 nodes/wave)

__global__ __launch_bounds__(256) void agg_linear(const uint32* __restrict__ h,
                                                  const int* __restrict__ rowptr,
                                                  const int* __restrict__ esrc,
                                                  const ushort16* __restrict__ Wbf,
                                                  const float* __restrict__ bias,
                                                  ushort16* __restrict__ hnext) {
    __shared__ uint32 xs[16][68];
    const int wave = threadIdx.x >> 6;
    const int lane = threadIdx.x & 63;
    const int m0 = blockIdx.x * 16;

#pragma unroll
    for (int j = 0; j < 4; ++j) {
        const int row = wave * 4 + j;
        const int node = __builtin_amdgcn_readfirstlane(m0 + row);
        const int beg = rowptr[node];
        const int end = rowptr[node + 1];
        const uint32 p = h[(long long)node * (D / 2) + lane];
        float acc0 = bflo(p), acc1 = bfhi(p);
        gather_rows(h, esrc, beg, end, lane, acc0, acc1);
        xs[row][lane] = ((uint32)f2bf(fmaxf(acc1, 0.f)) << 16) |
                        (uint32)f2bf(fmaxf(acc0, 0.f));
    }
    __syncthreads();

    const int lr = lane & 15;
    const int lk = (lane >> 4) * 8;
    f32x4 acc[2] = {};
#pragma unroll
    for (int k4 = 0; k4 < 4; ++k4) {
        const int kb = k4 * 32 + lk;
        const short8 af = *(const short8*)&xs[lr][kb >> 1];
#pragma unroll
        for (int f = 0; f < 2; ++f) {
            const int ft = wave * 2 + f;
            const short8 bfrag = *(const short8*)(Wbf + (ft * 16 + lr) * D + kb);
            acc[f] = __builtin_amdgcn_mfma_f32_16x16x32_bf16(af, bfrag, acc[f], 0, 0, 0);
        }
    }
    const int rbase = m0 + (lane >> 4) * 4;
#pragma unroll
    for (int f = 0; f < 2; ++f) {
        const int col = (wave * 2 + f) * 16 + lr;
        const float bb = bias[col];
#pragma unroll
        for (int r = 0; r < 4; ++r)
            hnext[(long long)(rbase + r) * D + col] = f2bf(acc[f][r] + bb);
    }
}

// ---- K6: last aggregate -> fp32 xe + fused head -------------------------

__global__ __launch_bounds__(256) void agg_head(const uint32* __restrict__ h,
                                                const int* __restrict__ rowptr,
                                                const int* __restrict__ esrc,
                                                float* __restrict__ xe,
                                                const float* __restrict__ Wout,
                                                const float* __restrict__ bout,
                                                float* __restrict__ logits,
                                                float* __restrict__ ypred) {
    const int wave = threadIdx.x >> 6;
    const int lane = threadIdx.x & 63;
    const int node = __builtin_amdgcn_readfirstlane(blockIdx.x * 4 + wave);
    if (node >= NN) return;
    const int beg = rowptr[node];
    const int end = rowptr[node + 1];
    const uint32 p = h[(long long)node * (D / 2) + lane];
    float acc0 = bflo(p), acc1 = bfhi(p);
    gather_rows(h, esrc, beg, end, lane, acc0, acc1);
    const float r0 = fmaxf(acc0, 0.f);
    const float r1 = fmaxf(acc1, 0.f);
    float2 r;
    r.x = r0;
    r.y = r1;
    ((float2*)(xe + (long long)node * D))[lane] = r;

    const float2 w0 = ((const float2*)(Wout + 0 * D))[lane];
    const float2 w1 = ((const float2*)(Wout + 1 * D))[lane];
    const float2 w2 = ((const float2*)(Wout + 2 * D))[lane];
    float l0 = r0 * w0.x + r1 * w0.y;
    float l1 = r0 * w1.x + r1 * w1.y;
    float l2 = r0 * w2.x + r1 * w2.y;
#pragma unroll
    for (int off = 32; off > 0; off >>= 1) {
        l0 += __shfl_xor(l0, off, 64);
        l1 += __shfl_xor(l1, off, 64);
        l2 += __shfl_xor(l2, off, 64);
    }
    if (lane == 0) {
        l0 += bout[0]; l1 += bout[1]; l2 += bout[2];
        logits[node * 3 + 0] = l0;
        logits[node * 3 + 1] = l1;
        logits[node * 3 + 2] = l2;
        int best = 0;
        float bv = l0;
        if (l1 > bv) { bv = l1; best = 1; }
        if (l2 > bv) { bv = l2; best = 2; }
        ypred[node] = (float)best;
    }
}

// ---- K7: epilogue gather ------------------------------------------------

__global__ void gather_out(const float* __restrict__ logits, const float* __restrict__ ypred,
                           const int* __restrict__ nidx, float* __restrict__ node_out,
                           float* __restrict__ y_nodepred) {
    const int m = blockIdx.x * blockDim.x + threadIdx.x;
    if (m >= MIDX) return;
    const int n = nidx[m];
    node_out[m * 3 + 0] = logits[n * 3 + 0];
    node_out[m * 3 + 1] = logits[n * 3 + 1];
    node_out[m * 3 + 2] = logits[n * 3 + 2];
    y_nodepred[m] = ypred[n];
}

extern "C" void kernel_launch(void* const* d_in, const int* in_sizes, int n_in,
                              void* d_out, int out_size, void* d_ws, size_t ws_size,
                              hipStream_t stream) {
    const float* x0 = (const float*)d_in[0];
    const int* ei = (const int*)d_in[1];
    const int* src = ei;        // edge_index[0]
    const int* dst = ei + EE;   // edge_index[1]
    const int* nidx = (const int*)d_in[3];
    const float* W1 = (const float*)d_in[4];
    const float* b1 = (const float*)d_in[5];
    const float* W2 = (const float*)d_in[6];
    const float* b2 = (const float*)d_in[7];
    const float* W3 = (const float*)d_in[8];
    const float* b3 = (const float*)d_in[9];
    const float* Wout = (const float*)d_in[10];
    const float* bout = (const float*)d_in[11];

    char* ws = (char*)d_ws;
    ushort16* hbuf = (ushort16*)ws;                                // N*D bf16  (buffer A)
    ushort16* xbuf = hbuf + (long long)NN * D;                     // N*D bf16  (buffer B)
    ushort16* Wbf  = xbuf + (long long)NN * D;                     // 3*D*D bf16
    float* logits  = (float*)(Wbf + 3 * D * D);                    // N*3
    int* rowptr    = (int*)(logits + (long long)NN * NCLS);        // NN+1 (+pad)
    int* gbucket   = rowptr + NN + 4;                              // 256
    int* bcursor   = gbucket + 256;                                // NB*16 (delta counters)
    int* espacked  = bcursor + NB * 16 + 12;                       // EE (16B align)
    int* esrc      = espacked + EE;                                // EE

    float* out = (float*)d_out;
    float* xe       = out;                       // N*D
    float* node_out = out + (long long)NN * D;   // M*3
    float* yp       = node_out + MIDX * NCLS;    // N
    float* ynp      = yp + NN;                   // M

    // ---- K0: zero gbucket + bcursor (contiguous, ~13 KB) ----
    hipMemsetAsync(gbucket, 0, (256 + NB * 16 + 12) * sizeof(int), stream);

    // ---- K1..K3: prep + CSR build (scatter overlapped with linear1) ----
    prep_hist<<<WCONV_WGS + HIST_WGS, 256, 0, stream>>>(W1, W2, W3, dst, Wbf, gbucket);
    fill_coarse<<<(EE + CHUNK - 1) / CHUNK, 256, 0, stream>>>(src, dst, gbucket,
                                                              bcursor, espacked);
    scatter_linear1<<<SCAT_WGS + LIN1_WGS, 256, 0, stream>>>(espacked, gbucket, rowptr,
                                                             esrc, x0, Wbf, b1, hbuf);

    // ---- K4..K7: layers + head ----
    agg_linear<<<NN / 16, 256, 0, stream>>>((const uint32*)hbuf, rowptr, esrc,
                                            Wbf + (long long)D * D, b2, xbuf);           // A -> B (h2)
    agg_linear<<<NN / 16, 256, 0, stream>>>((const uint32*)xbuf, rowptr, esrc,
                                            Wbf + 2LL * D * D, b3, hbuf);                // B -> A (h3)
    agg_head<<<(NN + 3) / 4, 256, 0, stream>>>((const uint32*)hbuf, rowptr, esrc,
                                               xe, Wout, bout, logits, yp);
    gather_out<<<(MIDX + 255) / 256, 256, 0, stream>>>(logits, yp, nidx, node_out, ynp);
}

// Round 13
// 164.140 us; speedup vs baseline: 1.1151x; 1.0649x over previous
//
#include <hip/hip_runtime.h>

#define NN 50000
#define EE 800000
#define D 128
#define NCLS 3
#define MIDX 10000
#define NB 196           // coarse buckets = ceil(NN/256)
#define CAP 8192         // padded slab capacity per bucket (max bucket ~4350)
#define CHUNK 4096       // edges per WG in fill
#define FILL_WGS 196     // ceil(EE/CHUNK)
#define WCONV_WGS 64     // D*D/256
#define SCAT_WGS NB
#define LIN1_WGS 782     // ceil(NN/64)

typedef unsigned int uint32;
typedef unsigned short ushort16;
typedef __attribute__((ext_vector_type(8))) short short8;
typedef __attribute__((ext_vector_type(4))) float f32x4;

__device__ __forceinline__ ushort16 f2bf(float f) {
    uint32 u = __float_as_uint(f);
    u = (u + 0x7fffu + ((u >> 16) & 1u)) >> 16;  // round-to-nearest-even
    return (ushort16)u;
}
__device__ __forceinline__ float bflo(uint32 packed) {
    return __uint_as_float(packed << 16);
}
__device__ __forceinline__ float bfhi(uint32 packed) {
    return __uint_as_float(packed & 0xFFFF0000u);
}

// full-wave gather, 16 row loads in flight (best measured variant)
__device__ __forceinline__ void gather_rows(const uint32* __restrict__ h,
                                            const int* __restrict__ esrc,
                                            int beg, int end, int lane,
                                            float& a0, float& a1) {
    int i = beg;
    for (; i + 16 <= end; i += 16) {
        int s[16];
        uint32 q[16];
#pragma unroll
        for (int k = 0; k < 16; ++k) s[k] = esrc[i + k];
#pragma unroll
        for (int k = 0; k < 16; ++k) q[k] = h[(long long)s[k] * (D / 2) + lane];
        float t0a = 0.f, t0b = 0.f, t1a = 0.f, t1b = 0.f;
#pragma unroll
        for (int k = 0; k < 16; k += 2) {
            t0a += bflo(q[k]);     t1a += bfhi(q[k]);
            t0b += bflo(q[k + 1]); t1b += bfhi(q[k + 1]);
        }
        a0 += t0a + t0b;
        a1 += t1a + t1b;
    }
    for (; i + 4 <= end; i += 4) {
        int s[4];
        uint32 q[4];
#pragma unroll
        for (int k = 0; k < 4; ++k) s[k] = esrc[i + k];
#pragma unroll
        for (int k = 0; k < 4; ++k) q[k] = h[(long long)s[k] * (D / 2) + lane];
        a0 += (bflo(q[0]) + bflo(q[1])) + (bflo(q[2]) + bflo(q[3]));
        a1 += (bfhi(q[0]) + bfhi(q[1])) + (bfhi(q[2]) + bfhi(q[3]));
    }
    for (; i < end; ++i) {
        const uint32 q = h[(long long)esrc[i] * (D / 2) + lane];
        a0 += bflo(q);
        a1 += bfhi(q);
    }
}

// ---- K1: blocks 0..FILL-1: padded-slab bucket fill; FILL..: W -> bf16 ---

__global__ __launch_bounds__(256) void fill_wconv(const int* __restrict__ src,
                                                  const int* __restrict__ dst,
                                                  const float* __restrict__ W1,
                                                  const float* __restrict__ W2,
                                                  const float* __restrict__ W3,
                                                  ushort16* __restrict__ Wbf,
                                                  int* __restrict__ bcursor,
                                                  int* __restrict__ espacked) {
    const int t = threadIdx.x;
    if (blockIdx.x >= FILL_WGS) {
        const int i = (blockIdx.x - FILL_WGS) * 256 + t;
        Wbf[i] = f2bf(W1[i]);
        Wbf[i + D * D] = f2bf(W2[i]);
        Wbf[i + 2 * D * D] = f2bf(W3[i]);
        return;
    }
    __shared__ int hcnt[256];
    __shared__ int hbase[256];
    const int e0 = blockIdx.x * CHUNK;
    const int e1 = (e0 + CHUNK < EE) ? e0 + CHUNK : EE;
    hcnt[t] = 0;
    __syncthreads();
    for (int s = e0 + t; s < e1; s += 256) atomicAdd(&hcnt[dst[s] >> 8], 1);
    __syncthreads();
    if (t < NB) {
        const int c = hcnt[t];
        hbase[t] = c ? (t * CAP + atomicAdd(&bcursor[t * 16], c)) : 0;
    }
    hcnt[t] = 0;
    __syncthreads();
    for (int s = e0 + t; s < e1; s += 256) {
        const int d = dst[s];
        const int b = d >> 8;
        const int r = atomicAdd(&hcnt[b], 1);
        espacked[hbase[b] + r] = (src[s] << 8) | (d & 255);
    }
}

// ---- K2: blocks 0..NB-1 = in-bucket scatter -> rowrng/esrc; rest = linear1

__global__ __launch_bounds__(256) void scatter_linear1(const int* __restrict__ espacked,
                                                       const int* __restrict__ bcursor,
                                                       int2* __restrict__ rowrng,
                                                       int* __restrict__ esrc,
                                                       const float* __restrict__ x,
                                                       const ushort16* __restrict__ Wbf,
                                                       const float* __restrict__ bias,
                                                       ushort16* __restrict__ h) {
    const int t = threadIdx.x;
    if (blockIdx.x < SCAT_WGS) {
        __shared__ int sc[256];
        __shared__ int cnt[256];
        __shared__ int cur[256];
        const int b = blockIdx.x;
        const int seg0 = b * CAP;
        const int seg1 = seg0 + bcursor[b * 16];  // slab occupancy
        const int n0 = b * 256;
        cnt[t] = 0;
        __syncthreads();
        for (int s = seg0 + t; s < seg1; s += 256) atomicAdd(&cnt[espacked[s] & 255], 1);
        __syncthreads();
        const int c = cnt[t];
        sc[t] = c;
        __syncthreads();
        for (int off = 1; off < 256; off <<= 1) {
            const int add = (t >= off) ? sc[t - off] : 0;
            __syncthreads();
            sc[t] += add;
            __syncthreads();
        }
        const int beg = seg0 + sc[t] - c;
        if (n0 + t < NN) rowrng[n0 + t] = make_int2(beg, beg + c);
        cur[t] = beg;
        __syncthreads();
        for (int s = seg0 + t; s < seg1; s += 256) {
            const int p = espacked[s];
            const int pos = atomicAdd(&cur[p & 255], 1);
            esrc[pos] = p >> 8;
        }
        return;
    }
    // ---- linear1: h1 = bf16(x0 @ W1^T + b1), fp32 input ----
    const int wave = t >> 6;
    const int lane = t & 63;
    const int m0 = (blockIdx.x - SCAT_WGS) * 64 + wave * 16;
    if (m0 >= NN) return;
    const int lr = lane & 15;
    const int lk = (lane >> 4) * 8;

    f32x4 acc[8] = {};
#pragma unroll
    for (int k4 = 0; k4 < 4; ++k4) {
        const int kb = k4 * 32 + lk;
        const float4* xp = (const float4*)(x + (long long)(m0 + lr) * D + kb);
        const float4 a0 = xp[0];
        const float4 a1 = xp[1];
        short8 af;
        af[0] = (short)f2bf(a0.x); af[1] = (short)f2bf(a0.y);
        af[2] = (short)f2bf(a0.z); af[3] = (short)f2bf(a0.w);
        af[4] = (short)f2bf(a1.x); af[5] = (short)f2bf(a1.y);
        af[6] = (short)f2bf(a1.z); af[7] = (short)f2bf(a1.w);
#pragma unroll
        for (int nt = 0; nt < 8; ++nt) {
            const short8 bfrag = *(const short8*)(Wbf + (nt * 16 + lr) * D + kb);
            acc[nt] = __builtin_amdgcn_mfma_f32_16x16x32_bf16(af, bfrag, acc[nt], 0, 0, 0);
        }
    }
    const int rbase = m0 + (lane >> 4) * 4;
#pragma unroll
    for (int nt = 0; nt < 8; ++nt) {
        const int f = nt * 16 + lr;
        const float bb = bias[f];
#pragma unroll
        for (int r = 0; r < 4; ++r)
            h[(long long)(rbase + r) * D + f] = f2bf(acc[nt][r] + bb);
    }
}

// ---- K3/K4: FUSED aggregate -> relu -> LDS tile -> MFMA next linear -----

__global__ __launch_bounds__(256) void agg_linear(const uint32* __restrict__ h,
                                                  const int2* __restrict__ rowrng,
                                                  const int* __restrict__ esrc,
                                                  const ushort16* __restrict__ Wbf,
                                                  const float* __restrict__ bias,
                                                  ushort16* __restrict__ hnext) {
    __shared__ uint32 xs[16][68];
    const int wave = threadIdx.x >> 6;
    const int lane = threadIdx.x & 63;
    const int m0 = blockIdx.x * 16;

#pragma unroll
    for (int j = 0; j < 4; ++j) {
        const int row = wave * 4 + j;
        const int node = __builtin_amdgcn_readfirstlane(m0 + row);
        const int2 rr = rowrng[node];
        const uint32 p = h[(long long)node * (D / 2) + lane];
        float acc0 = bflo(p), acc1 = bfhi(p);
        gather_rows(h, esrc, rr.x, rr.y, lane, acc0, acc1);
        xs[row][lane] = ((uint32)f2bf(fmaxf(acc1, 0.f)) << 16) |
                        (uint32)f2bf(fmaxf(acc0, 0.f));
    }
    __syncthreads();

    const int lr = lane & 15;
    const int lk = (lane >> 4) * 8;
    f32x4 acc[2] = {};
#pragma unroll
    for (int k4 = 0; k4 < 4; ++k4) {
        const int kb = k4 * 32 + lk;
        const short8 af = *(const short8*)&xs[lr][kb >> 1];
#pragma unroll
        for (int f = 0; f < 2; ++f) {
            const int ft = wave * 2 + f;
            const short8 bfrag = *(const short8*)(Wbf + (ft * 16 + lr) * D + kb);
            acc[f] = __builtin_amdgcn_mfma_f32_16x16x32_bf16(af, bfrag, acc[f], 0, 0, 0);
        }
    }
    const int rbase = m0 + (lane >> 4) * 4;
#pragma unroll
    for (int f = 0; f < 2; ++f) {
        const int col = (wave * 2 + f) * 16 + lr;
        const float bb = bias[col];
#pragma unroll
        for (int r = 0; r < 4; ++r)
            hnext[(long long)(rbase + r) * D + col] = f2bf(acc[f][r] + bb);
    }
}

// ---- K5: last aggregate -> fp32 xe + fused head -------------------------

__global__ __launch_bounds__(256) void agg_head(const uint32* __restrict__ h,
                                                const int2* __restrict__ rowrng,
                                                const int* __restrict__ esrc,
                                                float* __restrict__ xe,
                                                const float* __restrict__ Wout,
                                                const float* __restrict__ bout,
                                                float* __restrict__ logits,
                                                float* __restrict__ ypred) {
    const int wave = threadIdx.x >> 6;
    const int lane = threadIdx.x & 63;
    const int node = __builtin_amdgcn_readfirstlane(blockIdx.x * 4 + wave);
    if (node >= NN) return;
    const int2 rr = rowrng[node];
    const uint32 p = h[(long long)node * (D / 2) + lane];
    float acc0 = bflo(p), acc1 = bfhi(p);
    gather_rows(h, esrc, rr.x, rr.y, lane, acc0, acc1);
    const float r0 = fmaxf(acc0, 0.f);
    const float r1 = fmaxf(acc1, 0.f);
    float2 r;
    r.x = r0;
    r.y = r1;
    ((float2*)(xe + (long long)node * D))[lane] = r;

    const float2 w0 = ((const float2*)(Wout + 0 * D))[lane];
    const float2 w1 = ((const float2*)(Wout + 1 * D))[lane];
    const float2 w2 = ((const float2*)(Wout + 2 * D))[lane];
    float l0 = r0 * w0.x + r1 * w0.y;
    float l1 = r0 * w1.x + r1 * w1.y;
    float l2 = r0 * w2.x + r1 * w2.y;
#pragma unroll
    for (int off = 32; off > 0; off >>= 1) {
        l0 += __shfl_xor(l0, off, 64);
        l1 += __shfl_xor(l1, off, 64);
        l2 += __shfl_xor(l2, off, 64);
    }
    if (lane == 0) {
        l0 += bout[0]; l1 += bout[1]; l2 += bout[2];
        logits[node * 3 + 0] = l0;
        logits[node * 3 + 1] = l1;
        logits[node * 3 + 2] = l2;
        int best = 0;
        float bv = l0;
        if (l1 > bv) { bv = l1; best = 1; }
        if (l2 > bv) { bv = l2; best = 2; }
        ypred[node] = (float)best;
    }
}

// ---- K6: epilogue gather ------------------------------------------------

__global__ void gather_out(const float* __restrict__ logits, const float* __restrict__ ypred,
                           const int* __restrict__ nidx, float* __restrict__ node_out,
                           float* __restrict__ y_nodepred) {
    const int m = blockIdx.x * blockDim.x + threadIdx.x;
    if (m >= MIDX) return;
    const int n = nidx[m];
    node_out[m * 3 + 0] = logits[n * 3 + 0];
    node_out[m * 3 + 1] = logits[n * 3 + 1];
    node_out[m * 3 + 2] = logits[n * 3 + 2];
    y_nodepred[m] = ypred[n];
}

extern "C" void kernel_launch(void* const* d_in, const int* in_sizes, int n_in,
                              void* d_out, int out_size, void* d_ws, size_t ws_size,
                              hipStream_t stream) {
    const float* x0 = (const float*)d_in[0];
    const int* ei = (const int*)d_in[1];
    const int* src = ei;        // edge_index[0]
    const int* dst = ei + EE;   // edge_index[1]
    const int* nidx = (const int*)d_in[3];
    const float* W1 = (const float*)d_in[4];
    const float* b1 = (const float*)d_in[5];
    const float* W2 = (const float*)d_in[6];
    const float* b2 = (const float*)d_in[7];
    const float* W3 = (const float*)d_in[8];
    const float* b3 = (const float*)d_in[9];
    const float* Wout = (const float*)d_in[10];
    const float* bout = (const float*)d_in[11];

    char* ws = (char*)d_ws;
    ushort16* hbuf = (ushort16*)ws;                                // N*D bf16  (buffer A)
    ushort16* xbuf = hbuf + (long long)NN * D;                     // N*D bf16  (buffer B)
    ushort16* Wbf  = xbuf + (long long)NN * D;                     // 3*D*D bf16
    float* logits  = (float*)(Wbf + 3 * D * D);                    // N*3
    int2* rowrng   = (int2*)(logits + (long long)NN * NCLS);       // NN int2
    int* bcursor   = (int*)(rowrng + NN);                          // NB*16 (+pad)
    int* espacked  = bcursor + NB * 16 + 12;                       // NB*CAP
    int* esrc      = espacked + NB * CAP;                          // NB*CAP

    float* out = (float*)d_out;
    float* xe       = out;                       // N*D
    float* node_out = out + (long long)NN * D;   // M*3
    float* yp       = node_out + MIDX * NCLS;    // N
    float* ynp      = yp + NN;                   // M

    // ---- K0: zero bucket cursors (~12.5 KB) ----
    hipMemsetAsync(bcursor, 0, (NB * 16 + 12) * sizeof(int), stream);

    // ---- K1/K2: padded-slab CSR build; W-conv and linear1 overlapped ----
    fill_wconv<<<FILL_WGS + WCONV_WGS, 256, 0, stream>>>(src, dst, W1, W2, W3,
                                                         Wbf, bcursor, espacked);
    scatter_linear1<<<SCAT_WGS + LIN1_WGS, 256, 0, stream>>>(espacked, bcursor, rowrng,
                                                             esrc, x0, Wbf, b1, hbuf);

    // ---- K3..K6: layers + head ----
    agg_linear<<<NN / 16, 256, 0, stream>>>((const uint32*)hbuf, rowrng, esrc,
                                            Wbf + (long long)D * D, b2, xbuf);           // A -> B (h2)
    agg_linear<<<NN / 16, 256, 0, stream>>>((const uint32*)xbuf, rowrng, esrc,
                                            Wbf + 2LL * D * D, b3, hbuf);                // B -> A (h3)
    agg_head<<<(NN + 3) / 4, 256, 0, stream>>>((const uint32*)hbuf, rowrng, esrc,
                                               xe, Wout, bout, logits, yp);
    gather_out<<<(MIDX + 255) / 256, 256, 0, stream>>>(logits, yp, nidx, node_out, ynp);
}